// Round 4
// baseline (559.059 us; speedup 1.0000x reference)
//
#include <hip/hip_runtime.h>

#define BB 2
#define CC 64
#define HH 128
#define WW 128
#define HWN (HH*WW)          // 16384
#define CHW (CC*HWN)         // 2^20

// deform tiling
#define BAND_H 8
#define HALO   8             // dilation 5 + guard 2 (offsets sigma~0.15; outliers take global fallback)
#define NBAND  (HH / BAND_H) // 16
#define LDS_ROWS (BAND_H + 2 * HALO)   // 24
#define CPB 2
#define PLANE (LDS_ROWS * WW + 4)      // 3076 floats, pad slot at rows*WW
#define OFFS 20              // interleaved offset stride per pixel (18 + 2 pad -> 80 B, 16B-aligned)

// osum tiling
#define OB_H 16
#define OB_HALO 7
#define OB_ROWS (OB_H + 2 * OB_HALO)   // 30

// Stage 1: osum = BN(bias(dw1x15)) + BN(bias(dw15x1)) + BN(bias(dw3x3)), LDS-banded
__global__ __launch_bounds__(256) void osum_kernel(const float* __restrict__ x,
    const float* __restrict__ w1, const float* __restrict__ b1, const float* __restrict__ s1, const float* __restrict__ g1,
    const float* __restrict__ w2, const float* __restrict__ b2, const float* __restrict__ s2, const float* __restrict__ g2,
    const float* __restrict__ w3, const float* __restrict__ b3, const float* __restrict__ s3, const float* __restrict__ g3,
    float* __restrict__ osum)
{
    __shared__ float xs[OB_ROWS * WW];   // 15 KB
    int bid  = blockIdx.x;               // < BB*CC*8
    int band = bid & 7;
    int bc   = bid >> 3;
    int c    = bc & (CC - 1);
    int bs   = band * OB_H;
    int r_lo = bs - OB_HALO; if (r_lo < 0) r_lo = 0;
    int r_hi = bs + OB_H + OB_HALO; if (r_hi > HH) r_hi = HH;
    int n4 = (r_hi - r_lo) * (WW / 4);

    const float* xp = x + (size_t)bc * HWN;
    const float4* src = (const float4*)(xp + r_lo * WW);
    for (int i = threadIdx.x; i < n4; i += 256) ((float4*)xs)[i] = src[i];
    __syncthreads();

    float W1[15], W2[15], W3[9];
    #pragma unroll
    for (int k = 0; k < 15; ++k) { W1[k] = w1[c * 15 + k]; W2[k] = w2[c * 15 + k]; }
    #pragma unroll
    for (int k = 0; k < 9; ++k) W3[k] = w3[c * 9 + k];
    float bb1 = b1[c], ss1 = s1[c], gg1 = g1[c];
    float bb2 = b2[c], ss2 = s2[c], gg2 = g2[c];
    float bb3 = b3[c], ss3 = s3[c], gg3 = g3[c];

    #pragma unroll
    for (int i = 0; i < (OB_H * WW) / 256; ++i) {    // 8 px/thread
        int p = bs * WW + i * 256 + threadIdx.x;
        int h = p >> 7;
        int w = p & (WW - 1);
        int lr = h - r_lo;

        float a1 = 0.f;
        #pragma unroll
        for (int k = 0; k < 15; ++k) {
            int ww_ = w + k - 7;
            if (ww_ >= 0 && ww_ < WW) a1 += xs[lr * WW + ww_] * W1[k];
        }
        float a2 = 0.f;
        #pragma unroll
        for (int k = 0; k < 15; ++k) {
            int hh_ = h + k - 7;
            if (hh_ >= 0 && hh_ < HH) a2 += xs[(hh_ - r_lo) * WW + w] * W2[k];
        }
        float a3 = 0.f;
        #pragma unroll
        for (int kh = 0; kh < 3; ++kh) {
            int hh_ = h + kh - 1;
            if (hh_ < 0 || hh_ >= HH) continue;
            #pragma unroll
            for (int kw = 0; kw < 3; ++kw) {
                int ww_ = w + kw - 1;
                if (ww_ >= 0 && ww_ < WW) a3 += xs[(hh_ - r_lo) * WW + ww_] * W3[kh * 3 + kw];
            }
        }
        osum[(size_t)bc * HWN + p] = (a1 + bb1) * ss1 + gg1
                                   + (a2 + bb2) * ss2 + gg2
                                   + (a3 + bb3) * ss3 + gg3;
    }
}

// Stage 2: off2[b][px][oc] (interleaved, stride 20) = BN(bias(1x1conv(osum, bal_w)))
// Block: 64-px tile, stages osum[64ic][64px] once (16 KB). Wave og covers oc group.
__global__ __launch_bounds__(256) void off_kernel(const float* __restrict__ osum,
    const float* __restrict__ balw, const float* __restrict__ balb,
    const float* __restrict__ s4, const float* __restrict__ g4,
    float* __restrict__ off2)
{
    __shared__ float ls[CC * 64];   // 16 KB
    int bid = blockIdx.x;           // < 512
    int b   = bid >> 8;
    int hw0 = (bid & 255) * 64;

    const float* src = osum + (size_t)b * CHW + hw0;
    #pragma unroll
    for (int i = 0; i < 4; ++i) {
        int idx = threadIdx.x + i * 256;      // < 1024 float4
        int row = idx >> 4, col4 = idx & 15;
        ((float4*)ls)[row * 16 + col4] = *(const float4*)(src + (size_t)row * HWN + col4 * 4);
    }
    __syncthreads();

    int px = threadIdx.x & 63;
    int og = __builtin_amdgcn_readfirstlane((int)(threadIdx.x >> 6));  // 0..3
    int start = (og < 2) ? og * 5 : 10 + (og - 2) * 4;
    int cnt   = (og < 2) ? 5 : 4;

    float acc[5] = {0.f, 0.f, 0.f, 0.f, 0.f};
    for (int ic = 0; ic < CC; ++ic) {
        float v = ls[ic * 64 + px];
        #pragma unroll
        for (int j = 0; j < 5; ++j)
            if (j < cnt) acc[j] += v * balw[(start + j) * CC + ic];  // uniform -> s_load
    }
    float* dst = off2 + ((size_t)b * HWN + hw0 + px) * OFFS;
    #pragma unroll
    for (int j = 0; j < 5; ++j)
        if (j < cnt) {
            int oc = start + j;
            dst[oc] = (acc[j] + balb[oc]) * s4[oc] + g4[oc];
        }
}

// Stage 3: deformable gather, 2 channels/block, geometry shared, XCD-pinned grid.
// bid = cpair*32 + bband  ->  XCD = bband%8: all 32 cpair blocks of a band share one XCD's L2.
__global__ __launch_bounds__(256, 6) void deform_kernel(
    const float* __restrict__ x,
    const float* __restrict__ off2,
    const float* __restrict__ dw2, const float* __restrict__ dw3,
    const float* __restrict__ dw4, const float* __restrict__ dw5,
    float* __restrict__ pre)
{
    __shared__ float xs[CPB * PLANE];          // 24.6 KB
    __shared__ float wls[36 * CPB];

    int bid   = blockIdx.x;
    int bband = bid & 31;
    int cp    = bid >> 5;
    int band  = bband & (NBAND - 1);
    int b     = bband >> 4;
    int c0    = cp * CPB;
    int bc0   = b * CC + c0;

    int r_lo = band * BAND_H - HALO; if (r_lo < 0) r_lo = 0;
    int r_hi = band * BAND_H + BAND_H + HALO; if (r_hi > HH) r_hi = HH;
    int rows = r_hi - r_lo;
    int n4   = rows * (WW / 4);

    const float* xp0 = x + (size_t)bc0 * HWN;
    const float* xp1 = xp0 + HWN;

    for (int cc = 0; cc < CPB; ++cc) {
        const float4* src = (const float4*)(x + (size_t)(bc0 + cc) * HWN + r_lo * WW);
        float4* dst = (float4*)(xs + cc * PLANE);
        for (int i = threadIdx.x; i < n4; i += 256) dst[i] = src[i];
    }
    if (threadIdx.x < CPB) xs[threadIdx.x * PLANE + rows * WW] = 0.f;  // pad slot (x0c=127,+1 on last row)
    if (threadIdx.x < 36 * CPB) {
        int cc = threadIdx.x & 1, tap = threadIdx.x >> 1;
        int di = tap / 9, k = tap - di * 9;
        const float* dws = (di == 0) ? dw2 : (di == 1) ? dw3 : (di == 2) ? dw4 : dw5;
        wls[tap * CPB + cc] = dws[(c0 + cc) * 9 + k];
    }
    __syncthreads();

    const float* offb = off2 + (size_t)b * HWN * OFFS;

    #pragma unroll 1
    for (int chunk = 0; chunk < (BAND_H * WW) / 256; ++chunk) {
        int p = band * (BAND_H * WW) + chunk * 256 + threadIdx.x;
        int h = p >> 7;
        int w = p & (WW - 1);

        const float* ob = offb + (size_t)p * OFFS;     // 80 B, 16B-aligned
        float4 A  = *(const float4*)(ob);
        float4 Bq = *(const float4*)(ob + 4);
        float4 Cq = *(const float4*)(ob + 8);
        float4 Dq = *(const float4*)(ob + 12);
        float2 Eq = *(const float2*)(ob + 16);
        float oy[9] = {A.x, A.z, Bq.x, Bq.z, Cq.x, Cq.z, Dq.x, Dq.z, Eq.x};
        float ox[9] = {A.y, A.w, Bq.y, Bq.w, Cq.y, Cq.w, Dq.y, Dq.w, Eq.y};

        float acc0 = 0.f, acc1 = 0.f;
        #pragma unroll 1
        for (int di = 0; di < 4; ++di) {
            float d = (float)(di + 2);
            #pragma unroll
            for (int k = 0; k < 9; ++k) {
                float kyf = (float)(k / 3 - 1);
                float kxf = (float)(k % 3 - 1);
                float py = oy[k] + (float)h + d * kyf;
                float px = ox[k] + (float)w + d * kxf;
                float y0f = floorf(py), x0f = floorf(px);
                float wy = py - y0f, wx = px - x0f;
                int y0 = (int)y0f, x0 = (int)x0f;
                int y1 = y0 + 1, x1 = x0 + 1;
                bool yv0 = (y0 >= 0) && (y0 < HH);
                bool yv1 = (y1 >= 0) && (y1 < HH);
                bool xv0 = (x0 >= 0) && (x0 < WW);
                bool xv1 = (x1 >= 0) && (x1 < WW);
                float cya = yv0 ? (1.f - wy) : (yv1 ? wy : 0.f);
                float cyb = (yv0 && yv1) ? wy : 0.f;
                float cxa = xv0 ? (1.f - wx) : (xv1 ? wx : 0.f);
                float cxb = (xv0 && xv1) ? wx : 0.f;
                int y0c = min(max(y0, 0), HH - 1);
                int y1c = min(max(y1, 0), HH - 1);
                int x0c = min(max(x0, 0), WW - 1);

                int r0 = y0c - r_lo, r1 = y1c - r_lo;
                float v00, v01, v10, v11, u00, u01, u10, u11;
                if (r0 >= 0 && y1c < r_hi) {               // fast path: LDS
                    int f0 = (r0 << 7) + x0c;
                    int f1 = (r1 << 7) + x0c;
                    v00 = xs[f0];         v01 = xs[f0 + 1];
                    v10 = xs[f1];         v11 = xs[f1 + 1];
                    u00 = xs[PLANE + f0]; u01 = xs[PLANE + f0 + 1];
                    u10 = xs[PLANE + f1]; u11 = xs[PLANE + f1 + 1];
                } else {                                   // rare fallback (|off| > ~2)
                    int xn = min(x0c + 1, WW - 1);
                    int i00 = y0c * WW + x0c, i01 = y0c * WW + xn;
                    int i10 = y1c * WW + x0c, i11 = y1c * WW + xn;
                    v00 = xp0[i00]; v01 = xp0[i01]; v10 = xp0[i10]; v11 = xp0[i11];
                    u00 = xp1[i00]; u01 = xp1[i01]; u10 = xp1[i10]; u11 = xp1[i11];
                }
                float2 wl = *(const float2*)&wls[(di * 9 + k) * CPB];
                float s0 = cya * (cxa * v00 + cxb * v01) + cyb * (cxa * v10 + cxb * v11);
                float s1 = cya * (cxa * u00 + cxb * u01) + cyb * (cxa * u10 + cxb * u11);
                acc0 += s0 * wl.x;
                acc1 += s1 * wl.y;
            }
        }
        pre[((size_t)bc0 << 14) + p]       = acc0;
        pre[((size_t)(bc0 + 1) << 14) + p] = acc1;
    }
}

// Stage 4 (LDS-tiled): out = (BN(bias(1x1conv(pre, fin_w)))) * x
__global__ __launch_bounds__(256) void final_kernel(const float* __restrict__ pre,
    const float* __restrict__ finw, const float* __restrict__ finb,
    const float* __restrict__ s5, const float* __restrict__ g5,
    const float* __restrict__ x, float* __restrict__ out)
{
    __shared__ float ls[CC * 64];   // 16 KB
    int bid = blockIdx.x;           // < 512
    int b   = bid >> 8;
    int hw0 = (bid & 255) * 64;

    const float* src = pre + (size_t)b * CHW + hw0;
    #pragma unroll
    for (int i = 0; i < 4; ++i) {
        int idx = threadIdx.x + i * 256;      // < 1024 float4
        int row = idx >> 4, col4 = idx & 15;
        ((float4*)ls)[row * 16 + col4] = *(const float4*)(src + (size_t)row * HWN + col4 * 4);
    }
    __syncthreads();

    int hw = threadIdx.x & 63;
    int og = __builtin_amdgcn_readfirstlane((int)(threadIdx.x >> 6));  // 0..3

    float acc[16];
    #pragma unroll
    for (int j = 0; j < 16; ++j) acc[j] = 0.f;
    for (int ic = 0; ic < CC; ++ic) {
        float v = ls[ic * 64 + hw];
        #pragma unroll
        for (int j = 0; j < 16; ++j)
            acc[j] += v * finw[(og * 16 + j) * CC + ic];   // uniform -> s_load
    }
    #pragma unroll
    for (int j = 0; j < 16; ++j) {
        int oc = og * 16 + j;
        size_t oidx = ((size_t)(b * CC + oc) << 14) + hw0 + hw;
        out[oidx] = ((acc[j] + finb[oc]) * s5[oc] + g5[oc]) * x[oidx];
    }
}

extern "C" void kernel_launch(void* const* d_in, const int* in_sizes, int n_in,
                              void* d_out, int out_size, void* d_ws, size_t ws_size,
                              hipStream_t stream) {
    const float* x      = (const float*)d_in[0];
    const float* off1_w = (const float*)d_in[1];
    const float* off1_b = (const float*)d_in[2];
    const float* bn1_s  = (const float*)d_in[3];
    const float* bn1_b  = (const float*)d_in[4];
    const float* off2_w = (const float*)d_in[5];
    const float* off2_b = (const float*)d_in[6];
    const float* bn2_s  = (const float*)d_in[7];
    const float* bn2_b  = (const float*)d_in[8];
    const float* off3_w = (const float*)d_in[9];
    const float* off3_b = (const float*)d_in[10];
    const float* bn3_s  = (const float*)d_in[11];
    const float* bn3_b  = (const float*)d_in[12];
    const float* bal_w  = (const float*)d_in[13];
    const float* bal_b  = (const float*)d_in[14];
    const float* bn4_s  = (const float*)d_in[15];
    const float* bn4_b  = (const float*)d_in[16];
    const float* dw2    = (const float*)d_in[17];
    const float* dw3    = (const float*)d_in[18];
    const float* dw4    = (const float*)d_in[19];
    const float* dw5    = (const float*)d_in[20];
    const float* fin_w  = (const float*)d_in[21];
    const float* fin_b  = (const float*)d_in[22];
    const float* bn5_s  = (const float*)d_in[23];
    const float* bn5_b  = (const float*)d_in[24];

    float* ws   = (float*)d_ws;
    float* osum = ws;                          // 2,097,152 floats (8 MB)
    float* pre  = ws;                          // aliases osum (dead after off_kernel)
    float* off2 = ws + (size_t)BB * CHW;       // 655,360 floats (2.6 MB)

    float* out = (float*)d_out;

    osum_kernel<<<BB * CC * (HH / OB_H), 256, 0, stream>>>(x,
        off1_w, off1_b, bn1_s, bn1_b,
        off2_w, off2_b, bn2_s, bn2_b,
        off3_w, off3_b, bn3_s, bn3_b, osum);
    off_kernel<<<BB * (HWN / 64), 256, 0, stream>>>(osum, bal_w, bal_b, bn4_s, bn4_b, off2);
    deform_kernel<<<(CC / CPB) * 32, 256, 0, stream>>>(x, off2, dw2, dw3, dw4, dw5, pre);
    final_kernel<<<BB * (HWN / 64), 256, 0, stream>>>(pre, fin_w, fin_b, bn5_s, bn5_b, x, out);
}

// Round 5
// 222.101 us; speedup vs baseline: 2.5171x; 2.5171x over previous
//
#include <hip/hip_runtime.h>

#define BB 2
#define CC 64
#define HH 128
#define WW 128
#define HWN (HH*WW)          // 16384
#define CHW (CC*HWN)         // 2^20

// deform tiling
#define BAND_H 8
#define HALO   8             // dilation 5 + guard ~2 (off sigma~0.15; outliers -> global fallback)
#define NBAND  (HH / BAND_H) // 16
#define LDS_ROWS (BAND_H + 2 * HALO)   // 24
#define PLANE (LDS_ROWS * WW + 4)      // 3076 floats (pad slot at rows*WW)

// osum tiling
#define OB_H 16
#define OB_HALO 7
#define OB_ROWS (OB_H + 2 * OB_HALO)   // 30

// Stage 1: osum = BN(bias(dw1x15)) + BN(bias(dw15x1)) + BN(bias(dw3x3)), LDS-banded
__global__ __launch_bounds__(256) void osum_kernel(const float* __restrict__ x,
    const float* __restrict__ w1, const float* __restrict__ b1, const float* __restrict__ s1, const float* __restrict__ g1,
    const float* __restrict__ w2, const float* __restrict__ b2, const float* __restrict__ s2, const float* __restrict__ g2,
    const float* __restrict__ w3, const float* __restrict__ b3, const float* __restrict__ s3, const float* __restrict__ g3,
    float* __restrict__ osum)
{
    __shared__ float xs[OB_ROWS * WW];   // 15 KB
    int bid  = blockIdx.x;               // < BB*CC*8
    int band = bid & 7;
    int bc   = bid >> 3;
    int c    = bc & (CC - 1);
    int bs   = band * OB_H;
    int r_lo = bs - OB_HALO; if (r_lo < 0) r_lo = 0;
    int r_hi = bs + OB_H + OB_HALO; if (r_hi > HH) r_hi = HH;
    int n4 = (r_hi - r_lo) * (WW / 4);

    const float* xp = x + (size_t)bc * HWN;
    const float4* src = (const float4*)(xp + r_lo * WW);
    for (int i = threadIdx.x; i < n4; i += 256) ((float4*)xs)[i] = src[i];
    __syncthreads();

    float W1[15], W2[15], W3[9];
    #pragma unroll
    for (int k = 0; k < 15; ++k) { W1[k] = w1[c * 15 + k]; W2[k] = w2[c * 15 + k]; }
    #pragma unroll
    for (int k = 0; k < 9; ++k) W3[k] = w3[c * 9 + k];
    float bb1 = b1[c], ss1 = s1[c], gg1 = g1[c];
    float bb2 = b2[c], ss2 = s2[c], gg2 = g2[c];
    float bb3 = b3[c], ss3 = s3[c], gg3 = g3[c];

    #pragma unroll
    for (int i = 0; i < (OB_H * WW) / 256; ++i) {    // 8 px/thread
        int p = bs * WW + i * 256 + threadIdx.x;
        int h = p >> 7;
        int w = p & (WW - 1);
        int lr = h - r_lo;

        float a1 = 0.f;
        #pragma unroll
        for (int k = 0; k < 15; ++k) {
            int ww_ = w + k - 7;
            if (ww_ >= 0 && ww_ < WW) a1 += xs[lr * WW + ww_] * W1[k];
        }
        float a2 = 0.f;
        #pragma unroll
        for (int k = 0; k < 15; ++k) {
            int hh_ = h + k - 7;
            if (hh_ >= 0 && hh_ < HH) a2 += xs[(hh_ - r_lo) * WW + w] * W2[k];
        }
        float a3 = 0.f;
        #pragma unroll
        for (int kh = 0; kh < 3; ++kh) {
            int hh_ = h + kh - 1;
            if (hh_ < 0 || hh_ >= HH) continue;
            #pragma unroll
            for (int kw = 0; kw < 3; ++kw) {
                int ww_ = w + kw - 1;
                if (ww_ >= 0 && ww_ < WW) a3 += xs[(hh_ - r_lo) * WW + ww_] * W3[kh * 3 + kw];
            }
        }
        osum[(size_t)bc * HWN + p] = (a1 + bb1) * ss1 + gg1
                                   + (a2 + bb2) * ss2 + gg2
                                   + (a3 + bb3) * ss3 + gg3;
    }
}

// Stage 2 (LDS-tiled): off[b,j,hw] PLANAR = BN(bias(1x1conv(osum, bal_w)))
// Block: 128-px tile, stages osum[64][128] once (32 KB). osum read ONCE total.
__global__ __launch_bounds__(256) void off_kernel(const float* __restrict__ osum,
    const float* __restrict__ balw, const float* __restrict__ balb,
    const float* __restrict__ s4, const float* __restrict__ g4,
    float* __restrict__ off)
{
    __shared__ float ls[CC * 128];   // 32 KB
    int bid = blockIdx.x;            // < 256
    int b   = bid >> 7;
    int hw0 = (bid & 127) * 128;

    const float* src = osum + (size_t)b * CHW + hw0;
    #pragma unroll
    for (int i = 0; i < 8; ++i) {
        int idx = threadIdx.x + i * 256;       // < 2048 float4
        int row = idx >> 5, col4 = idx & 31;
        ((float4*)ls)[row * 32 + col4] = *(const float4*)(src + (size_t)row * HWN + col4 * 4);
    }
    __syncthreads();

    int hw = (threadIdx.x & 63) + ((threadIdx.x >> 6) & 1) * 64;
    int og = __builtin_amdgcn_readfirstlane((int)(threadIdx.x >> 7));  // 0 or 1

    float acc[9];
    #pragma unroll
    for (int j = 0; j < 9; ++j) acc[j] = 0.f;
    for (int ic = 0; ic < CC; ++ic) {
        float v = ls[ic * 128 + hw];
        #pragma unroll
        for (int j = 0; j < 9; ++j)
            acc[j] += v * balw[(og * 9 + j) * CC + ic];   // uniform -> s_load
    }
    #pragma unroll
    for (int j = 0; j < 9; ++j) {
        int oc = og * 9 + j;
        off[(size_t)b * (18 * HWN) + (size_t)oc * HWN + hw0 + hw] =
            (acc[j] + balb[oc]) * s4[oc] + g4[oc];
    }
}

// Stage 3: deformable gather, ONE channel per block (R2 grid/traffic profile),
// lean factored-weight body (VGPR <= 64 -> 8 blocks/CU with 12.3 KB LDS).
// bid = (bc << 4) | band  (R2 order: FETCH was 18 MB, WRITE 8 MB).
__global__ __launch_bounds__(256) void deform_kernel(
    const float* __restrict__ x,
    const float* __restrict__ off,
    const float* __restrict__ dw2, const float* __restrict__ dw3,
    const float* __restrict__ dw4, const float* __restrict__ dw5,
    float* __restrict__ pre)
{
    __shared__ float xs[PLANE];                // 12.3 KB

    int bid  = blockIdx.x;
    int band = bid & (NBAND - 1);
    int bc   = bid >> 4;
    int c    = bc & (CC - 1);
    int b    = bc >> 6;

    int r_lo = band * BAND_H - HALO; if (r_lo < 0) r_lo = 0;
    int r_hi = band * BAND_H + BAND_H + HALO; if (r_hi > HH) r_hi = HH;
    int rows = r_hi - r_lo;
    int n4   = rows * (WW / 4);

    const float* xp = x + (size_t)bc * HWN;
    {
        const float4* src = (const float4*)(xp + r_lo * WW);
        for (int i = threadIdx.x; i < n4; i += 256) ((float4*)xs)[i] = src[i];
        if (threadIdx.x == 0) xs[rows * WW] = 0.f;   // pad slot (x0c=127 '+1' on last row)
    }
    __syncthreads();

    const float* offb = off + (size_t)b * (18 * HWN);

    #pragma unroll 1
    for (int chunk = 0; chunk < (BAND_H * WW) / 256; ++chunk) {
        int p = band * (BAND_H * WW) + chunk * 256 + threadIdx.x;
        int h = p >> 7;
        int w = p & (WW - 1);

        float oy[9], ox[9];
        #pragma unroll
        for (int k = 0; k < 9; ++k) {                   // planar, fully coalesced
            oy[k] = offb[((size_t)(2 * k) << 14) + p];
            ox[k] = offb[((size_t)(2 * k + 1) << 14) + p];
        }

        float acc = 0.f;
        #pragma unroll 1
        for (int di = 0; di < 4; ++di) {
            float d = (float)(di + 2);
            const float* dws = (di == 0) ? dw2 : (di == 1) ? dw3 : (di == 2) ? dw4 : dw5;
            #pragma unroll
            for (int k = 0; k < 9; ++k) {
                float kyf = (float)(k / 3 - 1);
                float kxf = (float)(k % 3 - 1);
                float py = oy[k] + (float)h + d * kyf;
                float px = ox[k] + (float)w + d * kxf;
                float y0f = floorf(py), x0f = floorf(px);
                float wy = py - y0f, wx = px - x0f;
                int y0 = (int)y0f, x0 = (int)x0f;
                int y1 = y0 + 1, x1 = x0 + 1;
                bool yv0 = (y0 >= 0) && (y0 < HH);
                bool yv1 = (y1 >= 0) && (y1 < HH);
                bool xv0 = (x0 >= 0) && (x0 < WW);
                bool xv1 = (x1 >= 0) && (x1 < WW);
                float cya = yv0 ? (1.f - wy) : (yv1 ? wy : 0.f);
                float cyb = (yv0 && yv1) ? wy : 0.f;
                float cxa = xv0 ? (1.f - wx) : (xv1 ? wx : 0.f);
                float cxb = (xv0 && xv1) ? wx : 0.f;
                int y0c = min(max(y0, 0), HH - 1);
                int y1c = min(max(y1, 0), HH - 1);
                int x0c = min(max(x0, 0), WW - 1);

                int r0 = y0c - r_lo, r1 = y1c - r_lo;
                float v00, v01, v10, v11;
                if (r0 >= 0 && y1c < r_hi) {               // fast path: LDS
                    int f0 = (r0 << 7) + x0c;
                    int f1 = (r1 << 7) + x0c;
                    v00 = xs[f0]; v01 = xs[f0 + 1];        // -> ds_read2
                    v10 = xs[f1]; v11 = xs[f1 + 1];
                } else {                                   // rare fallback (|off| > ~2)
                    int xn = min(x0c + 1, WW - 1);
                    v00 = xp[y0c * WW + x0c]; v01 = xp[y0c * WW + xn];
                    v10 = xp[y1c * WW + x0c]; v11 = xp[y1c * WW + xn];
                }
                float s = cya * (cxa * v00 + cxb * v01) + cyb * (cxa * v10 + cxb * v11);
                acc += s * dws[c * 9 + k];                 // block-uniform -> s_load
            }
        }
        pre[((size_t)bc << 14) + p] = acc;
    }
}

// Stage 4 (LDS-tiled): out = (BN(bias(1x1conv(pre, fin_w)))) * x
__global__ __launch_bounds__(256) void final_kernel(const float* __restrict__ pre,
    const float* __restrict__ finw, const float* __restrict__ finb,
    const float* __restrict__ s5, const float* __restrict__ g5,
    const float* __restrict__ x, float* __restrict__ out)
{
    __shared__ float ls[CC * 64];   // 16 KB
    int bid = blockIdx.x;           // < 512
    int b   = bid >> 8;
    int hw0 = (bid & 255) * 64;

    const float* src = pre + (size_t)b * CHW + hw0;
    #pragma unroll
    for (int i = 0; i < 4; ++i) {
        int idx = threadIdx.x + i * 256;      // < 1024 float4
        int row = idx >> 4, col4 = idx & 15;
        ((float4*)ls)[row * 16 + col4] = *(const float4*)(src + (size_t)row * HWN + col4 * 4);
    }
    __syncthreads();

    int hw = threadIdx.x & 63;
    int og = __builtin_amdgcn_readfirstlane((int)(threadIdx.x >> 6));  // 0..3

    float acc[16];
    #pragma unroll
    for (int j = 0; j < 16; ++j) acc[j] = 0.f;
    for (int ic = 0; ic < CC; ++ic) {
        float v = ls[ic * 64 + hw];
        #pragma unroll
        for (int j = 0; j < 16; ++j)
            acc[j] += v * finw[(og * 16 + j) * CC + ic];   // uniform -> s_load
    }
    #pragma unroll
    for (int j = 0; j < 16; ++j) {
        int oc = og * 16 + j;
        size_t oidx = ((size_t)(b * CC + oc) << 14) + hw0 + hw;
        out[oidx] = ((acc[j] + finb[oc]) * s5[oc] + g5[oc]) * x[oidx];
    }
}

extern "C" void kernel_launch(void* const* d_in, const int* in_sizes, int n_in,
                              void* d_out, int out_size, void* d_ws, size_t ws_size,
                              hipStream_t stream) {
    const float* x      = (const float*)d_in[0];
    const float* off1_w = (const float*)d_in[1];
    const float* off1_b = (const float*)d_in[2];
    const float* bn1_s  = (const float*)d_in[3];
    const float* bn1_b  = (const float*)d_in[4];
    const float* off2_w = (const float*)d_in[5];
    const float* off2_b = (const float*)d_in[6];
    const float* bn2_s  = (const float*)d_in[7];
    const float* bn2_b  = (const float*)d_in[8];
    const float* off3_w = (const float*)d_in[9];
    const float* off3_b = (const float*)d_in[10];
    const float* bn3_s  = (const float*)d_in[11];
    const float* bn3_b  = (const float*)d_in[12];
    const float* bal_w  = (const float*)d_in[13];
    const float* bal_b  = (const float*)d_in[14];
    const float* bn4_s  = (const float*)d_in[15];
    const float* bn4_b  = (const float*)d_in[16];
    const float* dw2    = (const float*)d_in[17];
    const float* dw3    = (const float*)d_in[18];
    const float* dw4    = (const float*)d_in[19];
    const float* dw5    = (const float*)d_in[20];
    const float* fin_w  = (const float*)d_in[21];
    const float* fin_b  = (const float*)d_in[22];
    const float* bn5_s  = (const float*)d_in[23];
    const float* bn5_b  = (const float*)d_in[24];

    float* ws   = (float*)d_ws;
    float* osum = ws;                              // 8 MB
    float* off  = ws + (size_t)BB * CHW;           // 2.25 MB (planar)
    float* pre  = off + (size_t)BB * 18 * HWN;     // 8 MB (no aliasing)

    float* out = (float*)d_out;

    osum_kernel<<<BB * CC * (HH / OB_H), 256, 0, stream>>>(x,
        off1_w, off1_b, bn1_s, bn1_b,
        off2_w, off2_b, bn2_s, bn2_b,
        off3_w, off3_b, bn3_s, bn3_b, osum);
    off_kernel<<<BB * (HWN / 128), 256, 0, stream>>>(osum, bal_w, bal_b, bn4_s, bn4_b, off);
    deform_kernel<<<BB * CC * NBAND, 256, 0, stream>>>(x, off, dw2, dw3, dw4, dw5, pre);
    final_kernel<<<BB * (HWN / 64), 256, 0, stream>>>(pre, fin_w, fin_b, bn5_s, bn5_b, x, out);
}

// Round 6
// 208.169 us; speedup vs baseline: 2.6856x; 1.0669x over previous
//
#include <hip/hip_runtime.h>

#define BB 2
#define CC 64
#define HH 128
#define WW 128
#define HWN (HH*WW)          // 16384
#define CHW (CC*HWN)         // 2^20

// deform tiling
#define BAND_H 8
#define HALO   8             // dilation 5 + guard ~2; outliers -> full-check fallback
#define NBAND  (HH / BAND_H) // 16
#define LDS_ROWS (BAND_H + 2 * HALO)   // 24
#define CPB 2
#define PLANE (LDS_ROWS * WW + 4)      // 3076 floats; pad slot at rows*WW (zeroed)

// osum tiling
#define OB_H 16
#define OB_HALO 7
#define OB_ROWS (OB_H + 2 * OB_HALO)   // 30

// Stage 1: osum = BN(bias(dw1x15)) + BN(bias(dw15x1)) + BN(bias(dw3x3)), LDS-banded
__global__ __launch_bounds__(256) void osum_kernel(const float* __restrict__ x,
    const float* __restrict__ w1, const float* __restrict__ b1, const float* __restrict__ s1, const float* __restrict__ g1,
    const float* __restrict__ w2, const float* __restrict__ b2, const float* __restrict__ s2, const float* __restrict__ g2,
    const float* __restrict__ w3, const float* __restrict__ b3, const float* __restrict__ s3, const float* __restrict__ g3,
    float* __restrict__ osum)
{
    __shared__ float xs[OB_ROWS * WW];   // 15 KB
    int bid  = blockIdx.x;               // < BB*CC*8
    int band = bid & 7;
    int bc   = bid >> 3;
    int c    = bc & (CC - 1);
    int bs   = band * OB_H;
    int r_lo = bs - OB_HALO; if (r_lo < 0) r_lo = 0;
    int r_hi = bs + OB_H + OB_HALO; if (r_hi > HH) r_hi = HH;
    int n4 = (r_hi - r_lo) * (WW / 4);

    const float* xp = x + (size_t)bc * HWN;
    const float4* src = (const float4*)(xp + r_lo * WW);
    for (int i = threadIdx.x; i < n4; i += 256) ((float4*)xs)[i] = src[i];
    __syncthreads();

    float W1[15], W2[15], W3[9];
    #pragma unroll
    for (int k = 0; k < 15; ++k) { W1[k] = w1[c * 15 + k]; W2[k] = w2[c * 15 + k]; }
    #pragma unroll
    for (int k = 0; k < 9; ++k) W3[k] = w3[c * 9 + k];
    float bb1 = b1[c], ss1 = s1[c], gg1 = g1[c];
    float bb2 = b2[c], ss2 = s2[c], gg2 = g2[c];
    float bb3 = b3[c], ss3 = s3[c], gg3 = g3[c];

    #pragma unroll
    for (int i = 0; i < (OB_H * WW) / 256; ++i) {    // 8 px/thread
        int p = bs * WW + i * 256 + threadIdx.x;
        int h = p >> 7;
        int w = p & (WW - 1);
        int lr = h - r_lo;

        float a1 = 0.f;
        #pragma unroll
        for (int k = 0; k < 15; ++k) {
            int ww_ = w + k - 7;
            if (ww_ >= 0 && ww_ < WW) a1 += xs[lr * WW + ww_] * W1[k];
        }
        float a2 = 0.f;
        #pragma unroll
        for (int k = 0; k < 15; ++k) {
            int hh_ = h + k - 7;
            if (hh_ >= 0 && hh_ < HH) a2 += xs[(hh_ - r_lo) * WW + w] * W2[k];
        }
        float a3 = 0.f;
        #pragma unroll
        for (int kh = 0; kh < 3; ++kh) {
            int hh_ = h + kh - 1;
            if (hh_ < 0 || hh_ >= HH) continue;
            #pragma unroll
            for (int kw = 0; kw < 3; ++kw) {
                int ww_ = w + kw - 1;
                if (ww_ >= 0 && ww_ < WW) a3 += xs[(hh_ - r_lo) * WW + ww_] * W3[kh * 3 + kw];
            }
        }
        osum[(size_t)bc * HWN + p] = (a1 + bb1) * ss1 + gg1
                                   + (a2 + bb2) * ss2 + gg2
                                   + (a3 + bb3) * ss3 + gg3;
    }
}

// Stage 2 (LDS-tiled): off[b,j,hw] PLANAR = BN(bias(1x1conv(osum, bal_w)))
__global__ __launch_bounds__(256) void off_kernel(const float* __restrict__ osum,
    const float* __restrict__ balw, const float* __restrict__ balb,
    const float* __restrict__ s4, const float* __restrict__ g4,
    float* __restrict__ off)
{
    __shared__ float ls[CC * 128];   // 32 KB
    int bid = blockIdx.x;            // < 256
    int b   = bid >> 7;
    int hw0 = (bid & 127) * 128;

    const float* src = osum + (size_t)b * CHW + hw0;
    #pragma unroll
    for (int i = 0; i < 8; ++i) {
        int idx = threadIdx.x + i * 256;       // < 2048 float4
        int row = idx >> 5, col4 = idx & 31;
        ((float4*)ls)[row * 32 + col4] = *(const float4*)(src + (size_t)row * HWN + col4 * 4);
    }
    __syncthreads();

    int hw = (threadIdx.x & 63) + ((threadIdx.x >> 6) & 1) * 64;
    int og = __builtin_amdgcn_readfirstlane((int)(threadIdx.x >> 7));  // 0 or 1

    float acc[9];
    #pragma unroll
    for (int j = 0; j < 9; ++j) acc[j] = 0.f;
    for (int ic = 0; ic < CC; ++ic) {
        float v = ls[ic * 128 + hw];
        #pragma unroll
        for (int j = 0; j < 9; ++j)
            acc[j] += v * balw[(og * 9 + j) * CC + ic];   // uniform -> s_load
    }
    #pragma unroll
    for (int j = 0; j < 9; ++j) {
        int oc = og * 9 + j;
        off[(size_t)b * (18 * HWN) + (size_t)oc * HWN + hw0 + hw] =
            (acc[j] + balb[oc]) * s4[oc] + g4[oc];
    }
}

// ---- Stage 3 helpers ----

// Full-check tap: y-validity + clamps + LDS-or-global, 2 channels.
__device__ __forceinline__ void full_tap(
    const float* __restrict__ xs, const float* __restrict__ xp0, const float* __restrict__ xp1,
    int r_lo, int r_hi, float wy, int y0, float cxa, float cxb, int x0c,
    float& s0, float& s1)
{
    int y1 = y0 + 1;
    bool yv0 = ((unsigned)y0 < (unsigned)HH);
    bool yv1 = ((unsigned)y1 < (unsigned)HH);
    float cya = yv0 ? (1.f - wy) : (yv1 ? wy : 0.f);
    float cyb = (yv0 && yv1) ? wy : 0.f;
    int y0c = min(max(y0, 0), HH - 1);
    int y1c = min(max(y1, 0), HH - 1);
    int r0 = y0c - r_lo, r1 = y1c - r_lo;
    float v00, v01, v10, v11, u00, u01, u10, u11;
    if (r0 >= 0 && y1c < r_hi) {
        int f0 = (r0 << 7) + x0c;
        int f1 = (r1 << 7) + x0c;
        v00 = xs[f0]; v01 = xs[f0 + 1];
        v10 = xs[f1]; v11 = xs[f1 + 1];
        u00 = xs[PLANE + f0]; u01 = xs[PLANE + f0 + 1];
        u10 = xs[PLANE + f1]; u11 = xs[PLANE + f1 + 1];
    } else {                                  // rare outlier / image border
        int xn = min(x0c + 1, WW - 1);
        int i00 = y0c * WW + x0c, i01 = y0c * WW + xn;
        int i10 = y1c * WW + x0c, i11 = y1c * WW + xn;
        v00 = xp0[i00]; v01 = xp0[i01]; v10 = xp0[i10]; v11 = xp0[i11];
        u00 = xp1[i00]; u01 = xp1[i01]; u10 = xp1[i10]; u11 = xp1[i11];
    }
    s0 = cya * (cxa * v00 + cxb * v01) + cyb * (cxa * v10 + cxb * v11);
    s1 = cya * (cxa * u00 + cxb * u01) + cyb * (cxa * u10 + cxb * u11);
}

// Chunk loop, templated: YSAFE bands (2..13) skip all y-validity in the fast
// path (LDS residency 0<=r0<rows-1 implies 0<=y0,y1<=127 there: r_lo>=8, r_hi<=120).
template<bool YSAFE>
__device__ __forceinline__ void deform_chunks(
    const float* __restrict__ x, const float* __restrict__ off,
    const float* __restrict__ dw2, const float* __restrict__ dw3,
    const float* __restrict__ dw4, const float* __restrict__ dw5,
    float* __restrict__ pre, const float* __restrict__ xs,
    int b, int bc0, int c0, int band, int r_lo, int r_hi)
{
    const float* xp0 = x + (size_t)bc0 * HWN;
    const float* xp1 = xp0 + HWN;
    const float* offb = off + (size_t)b * (18 * HWN);
    int rows = r_hi - r_lo;

    #pragma unroll 1
    for (int chunk = 0; chunk < (BAND_H * WW) / 256; ++chunk) {
        int p = band * (BAND_H * WW) + chunk * 256 + (int)threadIdx.x;
        float hf = (float)(p >> 7);
        float wf = (float)(p & (WW - 1));

        float oy[9], ox[9];
        #pragma unroll
        for (int k = 0; k < 9; ++k) {                   // planar, fully coalesced
            oy[k] = offb[((size_t)(2 * k) << 14) + p];
            ox[k] = offb[((size_t)(2 * k + 1) << 14) + p];
        }

        float acc0 = 0.f, acc1 = 0.f;
        #pragma unroll 1
        for (int di = 0; di < 4; ++di) {
            float d = (float)(di + 2);
            const float* dwp = (di == 0) ? dw2 : (di == 1) ? dw3 : (di == 2) ? dw4 : dw5;
            #pragma unroll
            for (int k = 0; k < 9; ++k) {
                float kyf = (float)(k / 3 - 1);
                float kxf = (float)(k % 3 - 1);
                float py = oy[k] + hf + d * kyf;
                float px = ox[k] + wf + d * kxf;
                float y0f = floorf(py), x0f = floorf(px);
                float wy = py - y0f, wx = px - x0f;
                int y0 = (int)y0f, x0 = (int)x0f;
                bool xv0 = ((unsigned)x0 < (unsigned)WW);
                bool xv1 = ((unsigned)(x0 + 1) < (unsigned)WW);
                float cxa = xv0 ? (1.f - wx) : (xv1 ? wx : 0.f);
                float cxb = (xv0 && xv1) ? wx : 0.f;
                int x0c = min(max(x0, 0), WW - 1);

                float s0, s1;
                if (YSAFE) {
                    int r0 = y0 - r_lo;
                    if ((unsigned)r0 < (unsigned)(rows - 1)) {   // in LDS => y-valid
                        int f0 = (r0 << 7) + x0c;
                        float v00 = xs[f0],          v01 = xs[f0 + 1];
                        float v10 = xs[f0 + WW],     v11 = xs[f0 + WW + 1];
                        float u00 = xs[PLANE + f0],      u01 = xs[PLANE + f0 + 1];
                        float u10 = xs[PLANE + f0 + WW], u11 = xs[PLANE + f0 + WW + 1];
                        float ra0 = cxa * v00 + cxb * v01;
                        float rb0 = cxa * v10 + cxb * v11;
                        float ra1 = cxa * u00 + cxb * u01;
                        float rb1 = cxa * u10 + cxb * u11;
                        s0 = ra0 + wy * (rb0 - ra0);
                        s1 = ra1 + wy * (rb1 - ra1);
                    } else {                                     // rare outlier
                        full_tap(xs, xp0, xp1, r_lo, r_hi, wy, y0, cxa, cxb, x0c, s0, s1);
                    }
                } else {
                    full_tap(xs, xp0, xp1, r_lo, r_hi, wy, y0, cxa, cxb, x0c, s0, s1);
                }
                acc0 += s0 * dwp[c0 * 9 + k];          // block-uniform -> s_load
                acc1 += s1 * dwp[(c0 + 1) * 9 + k];
            }
        }
        pre[((size_t)bc0 << 14) + p]       = acc0;
        pre[((size_t)(bc0 + 1) << 14) + p] = acc1;
    }
}

// Stage 3: deformable gather, 2 channels/block, geometry shared.
// bid = bcp*16 + band: band in low bits => XCD = band%8 (R5's clean locality).
__global__ __launch_bounds__(256) void deform_kernel(
    const float* __restrict__ x,
    const float* __restrict__ off,
    const float* __restrict__ dw2, const float* __restrict__ dw3,
    const float* __restrict__ dw4, const float* __restrict__ dw5,
    float* __restrict__ pre)
{
    __shared__ float xs[CPB * PLANE];          // 24.6 KB

    int bid  = blockIdx.x;                     // < 1024
    int band = bid & (NBAND - 1);
    int bcp  = bid >> 4;
    int cp   = bcp & 31;
    int b    = bcp >> 5;
    int c0   = cp * CPB;
    int bc0  = b * CC + c0;

    int r_lo = band * BAND_H - HALO; if (r_lo < 0) r_lo = 0;
    int r_hi = band * BAND_H + BAND_H + HALO; if (r_hi > HH) r_hi = HH;
    int rows = r_hi - r_lo;
    int n4   = rows * (WW / 4);

    #pragma unroll
    for (int cc = 0; cc < CPB; ++cc) {
        const float4* src = (const float4*)(x + (size_t)(bc0 + cc) * HWN + r_lo * WW);
        float4* dst = (float4*)(xs + cc * PLANE);
        for (int i = threadIdx.x; i < n4; i += 256) dst[i] = src[i];
    }
    if (threadIdx.x < CPB) xs[threadIdx.x * PLANE + rows * WW] = 0.f;  // pad slot
    __syncthreads();

    if (band >= 2 && band <= 13)
        deform_chunks<true >(x, off, dw2, dw3, dw4, dw5, pre, xs, b, bc0, c0, band, r_lo, r_hi);
    else
        deform_chunks<false>(x, off, dw2, dw3, dw4, dw5, pre, xs, b, bc0, c0, band, r_lo, r_hi);
}

// Stage 4 (LDS-tiled): out = (BN(bias(1x1conv(pre, fin_w)))) * x
__global__ __launch_bounds__(256) void final_kernel(const float* __restrict__ pre,
    const float* __restrict__ finw, const float* __restrict__ finb,
    const float* __restrict__ s5, const float* __restrict__ g5,
    const float* __restrict__ x, float* __restrict__ out)
{
    __shared__ float ls[CC * 64];   // 16 KB
    int bid = blockIdx.x;           // < 512
    int b   = bid >> 8;
    int hw0 = (bid & 255) * 64;

    const float* src = pre + (size_t)b * CHW + hw0;
    #pragma unroll
    for (int i = 0; i < 4; ++i) {
        int idx = threadIdx.x + i * 256;      // < 1024 float4
        int row = idx >> 4, col4 = idx & 15;
        ((float4*)ls)[row * 16 + col4] = *(const float4*)(src + (size_t)row * HWN + col4 * 4);
    }
    __syncthreads();

    int hw = threadIdx.x & 63;
    int og = __builtin_amdgcn_readfirstlane((int)(threadIdx.x >> 6));  // 0..3

    float acc[16];
    #pragma unroll
    for (int j = 0; j < 16; ++j) acc[j] = 0.f;
    for (int ic = 0; ic < CC; ++ic) {
        float v = ls[ic * 64 + hw];
        #pragma unroll
        for (int j = 0; j < 16; ++j)
            acc[j] += v * finw[(og * 16 + j) * CC + ic];   // uniform -> s_load
    }
    #pragma unroll
    for (int j = 0; j < 16; ++j) {
        int oc = og * 16 + j;
        size_t oidx = ((size_t)(b * CC + oc) << 14) + hw0 + hw;
        out[oidx] = ((acc[j] + finb[oc]) * s5[oc] + g5[oc]) * x[oidx];
    }
}

extern "C" void kernel_launch(void* const* d_in, const int* in_sizes, int n_in,
                              void* d_out, int out_size, void* d_ws, size_t ws_size,
                              hipStream_t stream) {
    const float* x      = (const float*)d_in[0];
    const float* off1_w = (const float*)d_in[1];
    const float* off1_b = (const float*)d_in[2];
    const float* bn1_s  = (const float*)d_in[3];
    const float* bn1_b  = (const float*)d_in[4];
    const float* off2_w = (const float*)d_in[5];
    const float* off2_b = (const float*)d_in[6];
    const float* bn2_s  = (const float*)d_in[7];
    const float* bn2_b  = (const float*)d_in[8];
    const float* off3_w = (const float*)d_in[9];
    const float* off3_b = (const float*)d_in[10];
    const float* bn3_s  = (const float*)d_in[11];
    const float* bn3_b  = (const float*)d_in[12];
    const float* bal_w  = (const float*)d_in[13];
    const float* bal_b  = (const float*)d_in[14];
    const float* bn4_s  = (const float*)d_in[15];
    const float* bn4_b  = (const float*)d_in[16];
    const float* dw2    = (const float*)d_in[17];
    const float* dw3    = (const float*)d_in[18];
    const float* dw4    = (const float*)d_in[19];
    const float* dw5    = (const float*)d_in[20];
    const float* fin_w  = (const float*)d_in[21];
    const float* fin_b  = (const float*)d_in[22];
    const float* bn5_s  = (const float*)d_in[23];
    const float* bn5_b  = (const float*)d_in[24];

    float* ws   = (float*)d_ws;
    float* osum = ws;                              // 8 MB
    float* off  = ws + (size_t)BB * CHW;           // 2.25 MB (planar)
    float* pre  = off + (size_t)BB * 18 * HWN;     // 8 MB (no aliasing)

    float* out = (float*)d_out;

    osum_kernel<<<BB * CC * (HH / OB_H), 256, 0, stream>>>(x,
        off1_w, off1_b, bn1_s, bn1_b,
        off2_w, off2_b, bn2_s, bn2_b,
        off3_w, off3_b, bn3_s, bn3_b, osum);
    off_kernel<<<BB * (HWN / 128), 256, 0, stream>>>(osum, bal_w, bal_b, bn4_s, bn4_b, off);
    deform_kernel<<<BB * (CC / CPB) * NBAND, 256, 0, stream>>>(x, off, dw2, dw3, dw4, dw5, pre);
    final_kernel<<<BB * (HWN / 64), 256, 0, stream>>>(pre, fin_w, fin_b, bn5_s, bn5_b, x, out);
}

// Round 7
// 161.951 us; speedup vs baseline: 3.4520x; 1.2854x over previous
//
#include <hip/hip_runtime.h>

#define BB 2
#define CC 64
#define HH 128
#define WW 128
#define HWN (HH*WW)          // 16384
#define CHW (CC*HWN)         // 2^20

// deform tiling
#define BAND_H 8
#define HALO   8             // dilation 5 + bilinear 1 + guard 2; outliers -> global fallback
#define NBAND  (HH / BAND_H) // 16
#define LROWS  (BAND_H + 2 * HALO)     // 24
#define CPB    2
#define XPAD   8
#define XSTR   (WW + 2 * XPAD)         // 144 (zero-padded row, 16B-aligned)
// interleaved LDS: float2 {ch0,ch1} per texel; total 24*144*2 floats = 27648 B

// osum tiling
#define OB_H 16
#define OB_HALO 7
#define OB_ROWS (OB_H + 2 * OB_HALO)   // 30
#define OSTR 144                        // 128 + 2*8 zero-pad cols

// Stage 1: osum = BN(bias(dw1x15)) + BN(bias(dw15x1)) + BN(bias(dw3x3))
// Zero-padded LDS band: all 39 taps unconditional (pad reads give 0, matching
// the reference's skip-outside-image semantics).
__global__ __launch_bounds__(256) void osum_kernel(const float* __restrict__ x,
    const float* __restrict__ w1, const float* __restrict__ b1, const float* __restrict__ s1, const float* __restrict__ g1,
    const float* __restrict__ w2, const float* __restrict__ b2, const float* __restrict__ s2, const float* __restrict__ g2,
    const float* __restrict__ w3, const float* __restrict__ b3, const float* __restrict__ s3, const float* __restrict__ g3,
    float* __restrict__ osum)
{
    __shared__ float xs[OB_ROWS * OSTR];   // 17280 B
    int bid  = blockIdx.x;                 // < BB*CC*8
    int band = bid & 7;
    int bc   = bid >> 3;
    int c    = bc & (CC - 1);
    int bs   = band * OB_H;
    int r_lo_v = bs - OB_HALO;             // virtual (may be <0)

    // zero-fill then interior copy
    for (int i = threadIdx.x; i < (OB_ROWS * OSTR) / 4; i += 256)
        ((float4*)xs)[i] = make_float4(0.f, 0.f, 0.f, 0.f);
    __syncthreads();

    int gstart = r_lo_v < 0 ? 0 : r_lo_v;
    int gend   = r_lo_v + OB_ROWS; if (gend > HH) gend = HH;
    int nitems = (gend - gstart) * (WW / 4);
    const float* xp = x + (size_t)bc * HWN;
    for (int i = threadIdx.x; i < nitems; i += 256) {
        int r = i >> 5, col4 = i & 31;
        int g = gstart + r;
        int lr = g - r_lo_v;
        ((float4*)xs)[lr * (OSTR / 4) + 2 + col4] = ((const float4*)(xp + g * WW))[col4];
    }
    __syncthreads();

    float W1[15], W2[15], W3[9];
    #pragma unroll
    for (int k = 0; k < 15; ++k) { W1[k] = w1[c * 15 + k]; W2[k] = w2[c * 15 + k]; }
    #pragma unroll
    for (int k = 0; k < 9; ++k) W3[k] = w3[c * 9 + k];
    float bb1 = b1[c], ss1 = s1[c], gg1 = g1[c];
    float bb2 = b2[c], ss2 = s2[c], gg2 = g2[c];
    float bb3 = b3[c], ss3 = s3[c], gg3 = g3[c];

    #pragma unroll
    for (int i = 0; i < (OB_H * WW) / 256; ++i) {    // 8 px/thread
        int p = bs * WW + i * 256 + threadIdx.x;
        int h = p >> 7;
        int w = p & (WW - 1);
        int lr = h - r_lo_v;                         // in [7, 23)
        int base = lr * OSTR + XPAD + w;

        float a1 = 0.f;
        #pragma unroll
        for (int k = 0; k < 15; ++k) a1 += xs[base + k - 7] * W1[k];
        float a2 = 0.f;
        #pragma unroll
        for (int k = 0; k < 15; ++k) a2 += xs[base + (k - 7) * OSTR] * W2[k];
        float a3 = 0.f;
        #pragma unroll
        for (int kh = 0; kh < 3; ++kh)
            #pragma unroll
            for (int kw = 0; kw < 3; ++kw)
                a3 += xs[base + (kh - 1) * OSTR + (kw - 1)] * W3[kh * 3 + kw];

        osum[(size_t)bc * HWN + p] = (a1 + bb1) * ss1 + gg1
                                   + (a2 + bb2) * ss2 + gg2
                                   + (a3 + bb3) * ss3 + gg3;
    }
}

// Stage 2 (LDS-tiled): off[b,j,hw] PLANAR = BN(bias(1x1conv(osum, bal_w)))
__global__ __launch_bounds__(256) void off_kernel(const float* __restrict__ osum,
    const float* __restrict__ balw, const float* __restrict__ balb,
    const float* __restrict__ s4, const float* __restrict__ g4,
    float* __restrict__ off)
{
    __shared__ float ls[CC * 128];   // 32 KB
    int bid = blockIdx.x;            // < 256
    int b   = bid >> 7;
    int hw0 = (bid & 127) * 128;

    const float* src = osum + (size_t)b * CHW + hw0;
    #pragma unroll
    for (int i = 0; i < 8; ++i) {
        int idx = threadIdx.x + i * 256;       // < 2048 float4
        int row = idx >> 5, col4 = idx & 31;
        ((float4*)ls)[row * 32 + col4] = *(const float4*)(src + (size_t)row * HWN + col4 * 4);
    }
    __syncthreads();

    int hw = (threadIdx.x & 63) + ((threadIdx.x >> 6) & 1) * 64;
    int og = __builtin_amdgcn_readfirstlane((int)(threadIdx.x >> 7));  // 0 or 1

    float acc[9];
    #pragma unroll
    for (int j = 0; j < 9; ++j) acc[j] = 0.f;
    for (int ic = 0; ic < CC; ++ic) {
        float v = ls[ic * 128 + hw];
        #pragma unroll
        for (int j = 0; j < 9; ++j)
            acc[j] += v * balw[(og * 9 + j) * CC + ic];   // uniform -> s_load
    }
    #pragma unroll
    for (int j = 0; j < 9; ++j) {
        int oc = og * 9 + j;
        off[(size_t)b * (18 * HWN) + (size_t)oc * HWN + hw0 + hw] =
            (acc[j] + balb[oc]) * s4[oc] + g4[oc];
    }
}

// zero-padded global gather (exact: reference mask*clamp == zero-pad sampling)
__device__ __forceinline__ float gz(const float* __restrict__ xp, int y, int x) {
    return ((unsigned)y < (unsigned)HH && (unsigned)x < (unsigned)WW) ? xp[y * WW + x] : 0.f;
}

// Stage 3: deformable gather. 2 ch/block (interleaved in LDS), zero-padded
// tile (no validity ops in fast path), frac shared across dilations.
// bid = bcp*16 + band: band in low bits => XCD = band%8 (R5/R6 locality).
__global__ __launch_bounds__(256) void deform_kernel(
    const float* __restrict__ x,
    const float* __restrict__ off,
    const float* __restrict__ dw2, const float* __restrict__ dw3,
    const float* __restrict__ dw4, const float* __restrict__ dw5,
    float* __restrict__ pre)
{
    __shared__ float xs[LROWS * XSTR * CPB];   // 27648 B, float2-interleaved

    int bid  = blockIdx.x;                     // < 1024
    int band = bid & (NBAND - 1);
    int bcp  = bid >> 4;
    int cp   = bcp & 31;
    int b    = bcp >> 5;
    int c0   = cp * CPB;
    int bc0  = b * CC + c0;

    int r_lo_v = band * BAND_H - HALO;         // virtual (may be <0 / >HH-LROWS)

    // zero-fill pads + OOB rows
    for (int i = threadIdx.x; i < (LROWS * XSTR * CPB) / 4; i += 256)
        ((float4*)xs)[i] = make_float4(0.f, 0.f, 0.f, 0.f);
    __syncthreads();

    // interior fill, channel-interleaved: float4 idx = lr*72 + 4 + col4*2
    int gstart = r_lo_v < 0 ? 0 : r_lo_v;
    int gend   = r_lo_v + LROWS; if (gend > HH) gend = HH;
    int nitems = (gend - gstart) * (WW / 4);
    const float* xp0 = x + (size_t)bc0 * HWN;
    const float* xp1 = xp0 + HWN;
    for (int i = threadIdx.x; i < nitems; i += 256) {
        int r = i >> 5, col4 = i & 31;
        int g = gstart + r;
        int lr = g - r_lo_v;
        float4 q0 = ((const float4*)(xp0 + g * WW))[col4];
        float4 q1 = ((const float4*)(xp1 + g * WW))[col4];
        ((float4*)xs)[lr * (XSTR / 2) + XPAD / 2 + col4 * 2]     = make_float4(q0.x, q1.x, q0.y, q1.y);
        ((float4*)xs)[lr * (XSTR / 2) + XPAD / 2 + col4 * 2 + 1] = make_float4(q0.z, q1.z, q0.w, q1.w);
    }
    __syncthreads();

    const float2* XS2 = (const float2*)xs;
    const float* offb = off + (size_t)b * (18 * HWN);

    #pragma unroll 1
    for (int chunk = 0; chunk < (BAND_H * WW) / 256; ++chunk) {
        int p = band * (BAND_H * WW) + chunk * 256 + (int)threadIdx.x;
        float hf = (float)(p >> 7);
        float wf = (float)(p & (WW - 1));

        float oy[9], ox[9];
        #pragma unroll
        for (int k = 0; k < 9; ++k) {                   // planar, fully coalesced
            oy[k] = offb[((size_t)(2 * k) << 14) + p];
            ox[k] = offb[((size_t)(2 * k + 1) << 14) + p];
        }

        float acc0 = 0.f, acc1 = 0.f;
        #pragma unroll
        for (int k = 0; k < 9; ++k) {
            const int ky = k / 3 - 1, kx = k % 3 - 1;
            // d*ky is an integer => frac/floor/bilinear weights shared over di
            float pyb = oy[k] + hf;
            float pxb = ox[k] + wf;
            float y0f = floorf(pyb), x0f = floorf(pxb);
            float wy = pyb - y0f, wx = pxb - x0f;
            int y0g = (int)y0f, x0g = (int)x0f;
            int y0b = y0g - r_lo_v;                      // LDS row of di-contribution base
            int x0b = x0g + XPAD;                        // LDS col
            float cxa = 1.f - wx, cxb = wx;

            // one residency check covers all 4 dilations (extremes compile-time)
            const int dkyLo = (ky < 0) ? -5 : (ky > 0 ? 2 : 0);
            const int dkyHi = (ky < 0) ? -2 : (ky > 0 ? 5 : 0);
            const int dkxLo = (kx < 0) ? -5 : (kx > 0 ? 2 : 0);
            const int dkxHi = (kx < 0) ? -2 : (kx > 0 ? 5 : 0);
            bool ok = (y0b + dkyLo >= 0) & (y0b + dkyHi <= LROWS - 2)
                    & (x0b + dkxLo >= 0) & (x0b + dkxHi <= XSTR - 2);

            if (ok) {
                #pragma unroll
                for (int di = 0; di < 4; ++di) {
                    const int d = di + 2;
                    int f0 = (y0b + d * ky) * XSTR + (x0b + d * kx);
                    float2 a  = XS2[f0],        bq = XS2[f0 + 1];
                    float2 cq = XS2[f0 + XSTR], dq = XS2[f0 + XSTR + 1];
                    float ra0 = cxa * a.x + cxb * bq.x;
                    float rb0 = cxa * cq.x + cxb * dq.x;
                    float ra1 = cxa * a.y + cxb * bq.y;
                    float rb1 = cxa * cq.y + cxb * dq.y;
                    float s0 = ra0 + wy * (rb0 - ra0);
                    float s1 = ra1 + wy * (rb1 - ra1);
                    const float* dwp = (di == 0) ? dw2 : (di == 1) ? dw3 : (di == 2) ? dw4 : dw5;
                    acc0 += s0 * dwp[c0 * 9 + k];        // block-uniform -> s_load
                    acc1 += s1 * dwp[(c0 + 1) * 9 + k];
                }
            } else {                                     // rare outlier: global zero-pad
                #pragma unroll
                for (int di = 0; di < 4; ++di) {
                    const int d = di + 2;
                    int yy = y0g + d * ky, xx = x0g + d * kx;
                    float v00 = gz(xp0, yy, xx),     v01 = gz(xp0, yy, xx + 1);
                    float v10 = gz(xp0, yy + 1, xx), v11 = gz(xp0, yy + 1, xx + 1);
                    float u00 = gz(xp1, yy, xx),     u01 = gz(xp1, yy, xx + 1);
                    float u10 = gz(xp1, yy + 1, xx), u11 = gz(xp1, yy + 1, xx + 1);
                    float s0 = (1.f - wy) * (cxa * v00 + cxb * v01) + wy * (cxa * v10 + cxb * v11);
                    float s1 = (1.f - wy) * (cxa * u00 + cxb * u01) + wy * (cxa * u10 + cxb * u11);
                    const float* dwp = (di == 0) ? dw2 : (di == 1) ? dw3 : (di == 2) ? dw4 : dw5;
                    acc0 += s0 * dwp[c0 * 9 + k];
                    acc1 += s1 * dwp[(c0 + 1) * 9 + k];
                }
            }
        }
        pre[((size_t)bc0 << 14) + p]       = acc0;
        pre[((size_t)(bc0 + 1) << 14) + p] = acc1;
    }
}

// Stage 4 (LDS-tiled): out = (BN(bias(1x1conv(pre, fin_w)))) * x
__global__ __launch_bounds__(256) void final_kernel(const float* __restrict__ pre,
    const float* __restrict__ finw, const float* __restrict__ finb,
    const float* __restrict__ s5, const float* __restrict__ g5,
    const float* __restrict__ x, float* __restrict__ out)
{
    __shared__ float ls[CC * 64];   // 16 KB
    int bid = blockIdx.x;           // < 512
    int b   = bid >> 8;
    int hw0 = (bid & 255) * 64;

    const float* src = pre + (size_t)b * CHW + hw0;
    #pragma unroll
    for (int i = 0; i < 4; ++i) {
        int idx = threadIdx.x + i * 256;      // < 1024 float4
        int row = idx >> 4, col4 = idx & 15;
        ((float4*)ls)[row * 16 + col4] = *(const float4*)(src + (size_t)row * HWN + col4 * 4);
    }
    __syncthreads();

    int hw = threadIdx.x & 63;
    int og = __builtin_amdgcn_readfirstlane((int)(threadIdx.x >> 6));  // 0..3

    float acc[16];
    #pragma unroll
    for (int j = 0; j < 16; ++j) acc[j] = 0.f;
    for (int ic = 0; ic < CC; ++ic) {
        float v = ls[ic * 64 + hw];
        #pragma unroll
        for (int j = 0; j < 16; ++j)
            acc[j] += v * finw[(og * 16 + j) * CC + ic];   // uniform -> s_load
    }
    #pragma unroll
    for (int j = 0; j < 16; ++j) {
        int oc = og * 16 + j;
        size_t oidx = ((size_t)(b * CC + oc) << 14) + hw0 + hw;
        out[oidx] = ((acc[j] + finb[oc]) * s5[oc] + g5[oc]) * x[oidx];
    }
}

extern "C" void kernel_launch(void* const* d_in, const int* in_sizes, int n_in,
                              void* d_out, int out_size, void* d_ws, size_t ws_size,
                              hipStream_t stream) {
    const float* x      = (const float*)d_in[0];
    const float* off1_w = (const float*)d_in[1];
    const float* off1_b = (const float*)d_in[2];
    const float* bn1_s  = (const float*)d_in[3];
    const float* bn1_b  = (const float*)d_in[4];
    const float* off2_w = (const float*)d_in[5];
    const float* off2_b = (const float*)d_in[6];
    const float* bn2_s  = (const float*)d_in[7];
    const float* bn2_b  = (const float*)d_in[8];
    const float* off3_w = (const float*)d_in[9];
    const float* off3_b = (const float*)d_in[10];
    const float* bn3_s  = (const float*)d_in[11];
    const float* bn3_b  = (const float*)d_in[12];
    const float* bal_w  = (const float*)d_in[13];
    const float* bal_b  = (const float*)d_in[14];
    const float* bn4_s  = (const float*)d_in[15];
    const float* bn4_b  = (const float*)d_in[16];
    const float* dw2    = (const float*)d_in[17];
    const float* dw3    = (const float*)d_in[18];
    const float* dw4    = (const float*)d_in[19];
    const float* dw5    = (const float*)d_in[20];
    const float* fin_w  = (const float*)d_in[21];
    const float* fin_b  = (const float*)d_in[22];
    const float* bn5_s  = (const float*)d_in[23];
    const float* bn5_b  = (const float*)d_in[24];

    float* ws   = (float*)d_ws;
    float* osum = ws;                              // 8 MB
    float* off  = ws + (size_t)BB * CHW;           // 2.25 MB (planar)
    float* pre  = off + (size_t)BB * 18 * HWN;     // 8 MB

    float* out = (float*)d_out;

    osum_kernel<<<BB * CC * (HH / OB_H), 256, 0, stream>>>(x,
        off1_w, off1_b, bn1_s, bn1_b,
        off2_w, off2_b, bn2_s, bn2_b,
        off3_w, off3_b, bn3_s, bn3_b, osum);
    off_kernel<<<BB * (HWN / 128), 256, 0, stream>>>(osum, bal_w, bal_b, bn4_s, bn4_b, off);
    deform_kernel<<<BB * (CC / CPB) * NBAND, 256, 0, stream>>>(x, off, dw2, dw3, dw4, dw5, pre);
    final_kernel<<<BB * (HWN / 64), 256, 0, stream>>>(pre, fin_w, fin_b, bn5_s, bn5_b, x, out);
}